// Round 14
// baseline (42.157 us; speedup 1.0000x reference)
//
#include <hip/hip_runtime.h>
#include <math.h>

// InfiniteContextAttention — causal mask reaches only keys 0..15 (= compressed_k/v[:,:, :16]).
// Pipeline: q = hidden @ Wq^T -> 16-key causal attention -> out = attn @ Wo^T.
//
// v14 = v7 (37.4us, proven) with EXACTLY ONE change: fp32->bf16 conversion uses
// the REAL v_cvt_pk_bf16_f32 instruction via inline asm (1 instr / 2 elems,
// RNE) instead of 6-op hand-RNE per element. K-loop B-convert: 48 -> 4 VALU
// instrs per step; A-staging similarly cut.
// r13 lesson: __float22bfloat162_rn is SLOWER than hand-RNE (+4.2us) -> the
// conversion chain IS partially exposed at 2 waves/SIMD; cutting it below
// hand-RNE is the one untested direction with measured sensitivity.

#define HID 4096
#define NROW 32
#define NSLICE 8
#define KSL 512
#define NSTEP 16
#define PART_STRIDE (NROW * HID)  // 131072 floats per slice

typedef __attribute__((ext_vector_type(8))) short short8;
typedef __attribute__((ext_vector_type(4))) float f32x4;

// one v_cvt_pk_bf16_f32: packs RNE(lo) into [15:0], RNE(hi) into [31:16]
__device__ __forceinline__ unsigned cvtpk(float lo, float hi) {
    unsigned r;
    asm("v_cvt_pk_bf16_f32 %0, %1, %2" : "=v"(r) : "v"(lo), "v"(hi));
    return r;
}

__device__ __forceinline__ unsigned long long cvt4(float4 v) {
    return (unsigned long long)cvtpk(v.x, v.y)
         | ((unsigned long long)cvtpk(v.z, v.w) << 32);
}

__device__ __forceinline__ short8 cvt8(float4 a, float4 b) {
    union { short8 s; unsigned u[4]; } r;
    r.u[0] = cvtpk(a.x, a.y);
    r.u[1] = cvtpk(a.z, a.w);
    r.u[2] = cvtpk(b.x, b.y);
    r.u[3] = cvtpk(b.z, b.w);
    return r.s;
}

__global__ __launch_bounds__(256, 2)
void gemm_mfma(const float* __restrict__ A,   // [32][4096] fp32
               const float* __restrict__ W,   // [4096][4096] fp32
               float* __restrict__ P)         // [8][32][4096] fp32 partials
{
    __shared__ short As[NROW * KSL];  // 32 KB bf16, XOR-swizzled (T2)
    const int tid  = threadIdx.x;
    const int lane = tid & 63;
    const int wv   = tid >> 6;            // wave 0..3 -> 16-col tile
    const int cg   = blockIdx.x & 63;     // column group (64 cols)
    const int sl   = blockIdx.x >> 6;     // K-slice 0..7
    const int ks   = sl * KSL;

    // ---- stage A slice (fp32 -> bf16 via cvt_pk, swizzled) ----
    {
        const int r  = tid >> 3;          // row 0..31
        const int c8 = tid & 7;           // float4 column subgroup
        const float* src = A + (size_t)r * HID + ks + c8 * 4;
        char* lb = (char*)As + r * (KSL * 2);
        const int rx = (r & 7) << 4;
#pragma unroll
        for (int i = 0; i < 16; ++i) {
            float4 v = *(const float4*)(src + i * 32);
            int byte = ((c8 + 8 * i) * 8) ^ rx;
            *(unsigned long long*)(lb + byte) = cvt4(v);
        }
    }
    __syncthreads();  // the only barrier: LDS written once

    const int l15 = lane & 15, lq = lane >> 4, l7 = lane & 7;
    const int jcol = cg * 64 + wv * 16 + l15;
    const float* wp = W + (size_t)jcol * HID + ks + lq * 8;
    const char* lA0 = (const char*)As + l15 * (KSL * 2);
    const char* lA1 = (const char*)As + (16 + l15) * (KSL * 2);
    const int rswz = l7 << 4;

    f32x4 acc0 = {0.f, 0.f, 0.f, 0.f}, acc1 = {0.f, 0.f, 0.f, 0.f};

    // depth-3 rolling W prefetch (r7/r11: depth is a null knob; keep v7's form)
    float4 w0a = *(const float4*)(wp);
    float4 w0b = *(const float4*)(wp + 4);
    float4 w1a = *(const float4*)(wp + 32);
    float4 w1b = *(const float4*)(wp + 36);
    float4 w2a = *(const float4*)(wp + 64);
    float4 w2b = *(const float4*)(wp + 68);

#pragma unroll
    for (int kk = 0; kk < NSTEP; ++kk) {
        float4 nA = {}, nB = {};
        if (kk < NSTEP - 3) {
            nA = *(const float4*)(wp + (kk + 3) * 32);
            nB = *(const float4*)(wp + (kk + 3) * 32 + 4);
        }
        const int byte = ((kk * 64) + (lq * 16)) ^ rswz;
        short8 a0 = *(const short8*)(lA0 + byte);
        short8 a1 = *(const short8*)(lA1 + byte);
        short8 b = cvt8(w0a, w0b);   // 4x v_cvt_pk_bf16_f32 (was 48 VALU ops)
        acc0 = __builtin_amdgcn_mfma_f32_16x16x32_bf16(a0, b, acc0, 0, 0, 0);
        acc1 = __builtin_amdgcn_mfma_f32_16x16x32_bf16(a1, b, acc1, 0, 0, 0);
        w0a = w1a; w0b = w1b; w1a = w2a; w1b = w2b; w2a = nA; w2b = nB;
    }

    // ---- epilogue: C/D layout col=lane&15, row=(lane>>4)*4+reg (m89-verified) ----
    float* pout = P + (size_t)sl * PART_STRIDE + jcol;
#pragma unroll
    for (int rr = 0; rr < 4; ++rr) {
        pout[(size_t)(lq * 4 + rr) * HID]        = acc0[rr];
        pout[(size_t)(16 + lq * 4 + rr) * HID]   = acc1[rr];
    }
}

// One wave per (b,h,i): fuses the 8-slice q-reduction with 16-key causal attention.
__global__ __launch_bounds__(256)
void attn16_kernel(const float* __restrict__ P,   // q partials [8][32][4096]
                   const float* __restrict__ ck,
                   const float* __restrict__ cv,
                   float* __restrict__ o)          // [32][4096]
{
    const int lane = threadIdx.x & 63;
    const int g = blockIdx.x * 4 + (threadIdx.x >> 6);  // 0..1023
    const int b = g >> 9;
    const int h = (g >> 4) & 31;
    const int i = g & 15;

    const size_t qoff = ((size_t)(b * 16 + i)) * HID + h * 128 + 2 * lane;
    float2 q2 = {0.f, 0.f};
#pragma unroll
    for (int s = 0; s < NSLICE; ++s) {
        float2 p = *(const float2*)(P + (size_t)s * PART_STRIDE + qoff);
        q2.x += p.x; q2.y += p.y;
    }
    const size_t kvoff = ((size_t)(b * 32 + h)) * 2048 * 128 + 2 * lane;
    const float* kp = ck + kvoff;
    const float* vp = cv + kvoff;

    float e[16];
#pragma unroll
    for (int s = 0; s < 16; ++s) {
        float2 k2 = *(const float2*)(kp + (size_t)s * 128);
        float p = q2.x * k2.x + q2.y * k2.y;
#pragma unroll
        for (int m = 32; m >= 1; m >>= 1) p += __shfl_xor(p, m, 64);
        e[s] = (s <= i) ? p * 0.08838834764831845f : -3.4e38f;  // i wave-uniform
    }
    float mx = e[0];
#pragma unroll
    for (int s = 1; s < 16; ++s) mx = fmaxf(mx, e[s]);
    float den = 0.f;
#pragma unroll
    for (int s = 0; s < 16; ++s) { e[s] = __expf(e[s] - mx); den += e[s]; }
    const float inv = 1.0f / den;

    float ox = 0.f, oy = 0.f;
#pragma unroll
    for (int s = 0; s < 16; ++s) {
        float2 v2 = *(const float2*)(vp + (size_t)s * 128);
        ox += e[s] * v2.x;
        oy += e[s] * v2.y;
    }
    float2 res; res.x = ox * inv; res.y = oy * inv;
    *(float2*)(o + qoff) = res;
}

// out[i] = sum over 8 slices of P[s][i]; 32768 float4s.
__global__ __launch_bounds__(256)
void reduce8_kernel(const float* __restrict__ P, float* __restrict__ out)
{
    const int idx = blockIdx.x * 256 + threadIdx.x;  // float4 index
    const float4* p4 = (const float4*)P;
    float4 s = p4[idx];
#pragma unroll
    for (int t = 1; t < NSLICE; ++t) {
        float4 v = p4[idx + t * (PART_STRIDE / 4)];
        s.x += v.x; s.y += v.y; s.z += v.z; s.w += v.w;
    }
    ((float4*)out)[idx] = s;
}

extern "C" void kernel_launch(void* const* d_in, const int* in_sizes, int n_in,
                              void* d_out, int out_size, void* d_ws, size_t ws_size,
                              hipStream_t stream) {
    const float* hidden = (const float*)d_in[0];  // [2][16][4096]
    const float* ck     = (const float*)d_in[3];  // [2][32][2048][128]
    const float* cv     = (const float*)d_in[4];
    const float* Wq     = (const float*)d_in[5];  // [4096][4096]
    const float* Wo     = (const float*)d_in[8];
    float* out  = (float*)d_out;                  // [2][16][4096]
    float* part = (float*)d_ws;                   // [8][32][4096] = 4 MB
    float* abuf = part + NSLICE * PART_STRIDE;    // [32][4096] attn output

    hipLaunchKernelGGL(gemm_mfma,     dim3(512), dim3(256), 0, stream, hidden, Wq, part);
    hipLaunchKernelGGL(attn16_kernel, dim3(256), dim3(256), 0, stream, part, ck, cv, abuf);
    hipLaunchKernelGGL(gemm_mfma,     dim3(512), dim3(256), 0, stream, abuf, Wo, part);
    hipLaunchKernelGGL(reduce8_kernel,dim3(128), dim3(256), 0, stream, part, out);
}